// Round 2
// baseline (465.891 us; speedup 1.0000x reference)
//
#include <hip/hip_runtime.h>
#include <stdint.h>

// ContextPeftAdaptorLora on MI355X.
// Strategy: fold the 4 rank-16 LoRA adaptors into the K dimension of the base
// GEMM:  out = [x | mask*H] @ [W | 2*Bw]^T + b   with K' = 2048 + 64 = 2112.
// Pass1a: convert x->bf16 into Xaug AND compute PARTIAL H = x @ A^T (MFMA),
//         K split 4 ways -> 1024 blocks (4/CU) to hide barrier latency.
// Pass1b: reduce the 4 partials, apply per-adaptor mask, write Xaug H cols.
// Pass2:  convert W->bf16 and scaled Bw into Waug.
// Pass3:  T3+T4 deep-pipelined bf16 MFMA GEMM: BM=256 x BN=128, BK=64,
//         3-slot LDS ring (prefetch distance 2), ONE raw s_barrier and ONE
//         counted s_waitcnt vmcnt(6) per K-tile (never vmcnt(0) in steady
//         state), T2 XOR-swizzled global_load_lds staging (0 conflicts
//         measured), T5 setprio around MFMA clusters, T1 XCD block swizzle.

typedef __attribute__((ext_vector_type(8))) short bf16x8;   // 8 bf16 = 4 VGPR
typedef __attribute__((ext_vector_type(4))) float f32x4;    // MFMA C/D
typedef __attribute__((ext_vector_type(4))) unsigned short u16x4;
typedef __attribute__((ext_vector_type(8))) unsigned short u16x8;

#define GAS __attribute__((address_space(1)))
#define LAS __attribute__((address_space(3)))

static constexpr int BB   = 4;
static constexpr int SS   = 4096;
static constexpr int DIN  = 2048;
static constexpr int DOUT = 2048;
static constexpr int NADP = 4;
static constexpr int RR   = 16;
static constexpr int M    = BB * SS;          // 16384 rows
static constexpr int KA   = DIN + NADP * RR;  // 2112 augmented K
static constexpr float SCALE = 2.0f;          // lora_alpha / r

static constexpr int KSPLIT = 4;              // H K-reduction split factor
static constexpr int KCH    = DIN / KSPLIT;   // 512 K per block

static constexpr int NT    = KA / 64;         // 33 K-tiles in the GEMM
static constexpr int ASLOT = 256 * 64;        // ushorts per A ring slot (32 KB)
static constexpr int BSLOT = 128 * 64;        // ushorts per B ring slot (16 KB)

static_assert(KA % 64 == 0, "K-loop needs BK=64 divisibility");

__device__ __forceinline__ unsigned short f2bf(float f) {
  union { float f; uint32_t u; } v; v.f = f;
  uint32_t u = v.u;
  // round-to-nearest-even
  return (unsigned short)((u + 0x7FFFu + ((u >> 16) & 1u)) >> 16);
}

// ---------------------------------------------------------------------------
// Pass 1a: rows in blocks of 64, K in blocks of 512 (KSPLIT=4). Streams its
// x panel once: converts to bf16 (written to Xaug cols [kBase,kBase+512)) and
// accumulates partial H = x @ A_flat^T over its K slice via 16x16x32 bf16
// MFMA on staged LDS chunks. Epilogue writes f32 partials to Hpart[ks][M][64].
// ---------------------------------------------------------------------------
__global__ __launch_bounds__(256) void pass1a_conv_hpart(
    const float* __restrict__ x, const float* __restrict__ A,
    unsigned short* __restrict__ Xaug, float* __restrict__ Hpart)
{
  __shared__ unsigned short xb[64 * 64];  // [row][k] bf16, 8 KB
  __shared__ unsigned short ab[64 * 64];  // [j][k]   bf16, 8 KB

  const int tid = threadIdx.x;
  const int rb = blockIdx.x >> 2;         // 0..255 row-block
  const int ks = blockIdx.x & 3;          // 0..3   K-slice
  const int rowBase = rb * 64;
  const int kBase = ks * KCH;
  const int w = tid >> 6, lane = tid & 63;
  const int quad = lane >> 4, m16 = lane & 15;

  f32x4 acc[4];
  #pragma unroll
  for (int j = 0; j < 4; ++j) acc[j] = f32x4{0.f, 0.f, 0.f, 0.f};

  for (int kc = kBase; kc < kBase + KCH; kc += 64) {
    __syncthreads();  // protect LDS against overwrite while prior MFMA reads run
    #pragma unroll
    for (int l = 0; l < 4; ++l) {
      int v = l * 256 + tid;        // float4-chunk id, 0..1023
      int r = v >> 4;               // row (0..63)
      int k = (v & 15) * 4;         // k offset (0..60)
      float4 xv = *(const float4*)(x + (size_t)(rowBase + r) * DIN + kc + k);
      u16x4 xq = { f2bf(xv.x), f2bf(xv.y), f2bf(xv.z), f2bf(xv.w) };
      *(u16x4*)(xb + r * 64 + k) = xq;
      *(u16x4*)(Xaug + (size_t)(rowBase + r) * KA + kc + k) = xq;
      float4 av = *(const float4*)(A + (size_t)r * DIN + kc + k);  // j = r
      u16x4 aq = { f2bf(av.x), f2bf(av.y), f2bf(av.z), f2bf(av.w) };
      *(u16x4*)(ab + r * 64 + k) = aq;
    }
    __syncthreads();
    // wave w computes H rows [w*16, w*16+16) x all 64 j
    #pragma unroll
    for (int s = 0; s < 2; ++s) {
      bf16x8 af = *(const bf16x8*)(xb + (w * 16 + m16) * 64 + s * 32 + quad * 8);
      #pragma unroll
      for (int jt = 0; jt < 4; ++jt) {
        bf16x8 bfg = *(const bf16x8*)(ab + (jt * 16 + m16) * 64 + s * 32 + quad * 8);
        acc[jt] = __builtin_amdgcn_mfma_f32_16x16x32_bf16(af, bfg, acc[jt], 0, 0, 0);
      }
    }
  }

  // Epilogue: Hpart[ks][row][j] = partial H over this K slice.
  // C/D layout: col = lane&15, row = quad*4 + reg  [m89/m91 verified]
  const int grow0 = rowBase + w * 16 + quad * 4;
  #pragma unroll
  for (int jt = 0; jt < 4; ++jt) {
    #pragma unroll
    for (int r = 0; r < 4; ++r) {
      int grow = grow0 + r;
      Hpart[(((size_t)ks * M + grow) << 6) + jt * 16 + m16] = acc[jt][r];
    }
  }
}

// ---------------------------------------------------------------------------
// Pass 1b: H[row,j] = sum_ks Hpart[ks][row][j]; apply mask[n=j/16, row];
// write bf16 into Xaug cols [2048, 2112). ~17 MB read, 2 MB write.
// ---------------------------------------------------------------------------
__global__ __launch_bounds__(256) void pass1b_reduce_mask(
    const float* __restrict__ Hpart, const float* __restrict__ mask,
    unsigned short* __restrict__ Xaug)
{
  const int idx = blockIdx.x * 256 + threadIdx.x;  // 0 .. M*64-1
  const int row = idx >> 6;
  const int j   = idx & 63;
  float s = 0.f;
  #pragma unroll
  for (int ks = 0; ks < KSPLIT; ++ks)
    s += Hpart[(((size_t)ks * M) << 6) + idx];
  s *= mask[(size_t)(j >> 4) * M + row];
  Xaug[(size_t)row * KA + DIN + j] = f2bf(s);
}

// ---------------------------------------------------------------------------
// Pass 2: Waug[col, 0:2048) = bf16(W[col,:]);  Waug[col, 2048+n*16+r] =
// bf16(SCALE * Bw[n, col, r]).
// ---------------------------------------------------------------------------
__global__ __launch_bounds__(256) void pass2_wcvt(
    const float* __restrict__ W, const float* __restrict__ Bw,
    unsigned short* __restrict__ Waug)
{
  const int idx = blockIdx.x * 256 + threadIdx.x;  // 0..524287
  const int row = idx >> 8;          // 2048 rows, 256 8-elem chunks each
  const int k   = (idx & 255) * 8;
  float4 a = *(const float4*)(W + (size_t)row * DIN + k);
  float4 b = *(const float4*)(W + (size_t)row * DIN + k + 4);
  u16x8 q = { f2bf(a.x), f2bf(a.y), f2bf(a.z), f2bf(a.w),
              f2bf(b.x), f2bf(b.y), f2bf(b.z), f2bf(b.w) };
  *(u16x8*)(Waug + (size_t)row * KA + k) = q;

  if (idx < DOUT * NADP) {           // 8192 threads build the Bwcat columns
    const int col = idx >> 2, n = idx & 3;
    const float* src = Bw + (size_t)n * DOUT * RR + (size_t)col * RR;
    #pragma unroll
    for (int t = 0; t < 4; ++t) {
      float4 bv = *(const float4*)(src + 4 * t);
      u16x4 qq = { f2bf(SCALE * bv.x), f2bf(SCALE * bv.y),
                   f2bf(SCALE * bv.z), f2bf(SCALE * bv.w) };
      *(u16x4*)(Waug + (size_t)col * KA + DIN + n * 16 + 4 * t) = qq;
    }
  }
}

// ---------------------------------------------------------------------------
// Stage one K-tile (A: 256x64, B: 128x64 bf16) into ring slots via
// global_load_lds width=16. LDS dest is linear (wave-uniform base + lane*16);
// the XOR swizzle (chunk c' holds global chunk c'^(r&7)) is applied on the
// GLOBAL source address. 6 loads per thread per tile.
// ---------------------------------------------------------------------------
__device__ __forceinline__ void stage_tile(
    const unsigned short* __restrict__ ga, const unsigned short* __restrict__ gb,
    unsigned short* sa, unsigned short* sb, int k0,
    const int* goa, const int* loa, const int* gob, const int* lob)
{
  #pragma unroll
  for (int l = 0; l < 4; ++l)
    __builtin_amdgcn_global_load_lds((const GAS void*)(ga + goa[l] + k0),
                                     (LAS void*)(sa + loa[l]), 16, 0, 0);
  #pragma unroll
  for (int l = 0; l < 2; ++l)
    __builtin_amdgcn_global_load_lds((const GAS void*)(gb + gob[l] + k0),
                                     (LAS void*)(sb + lob[l]), 16, 0, 0);
}

// ---------------------------------------------------------------------------
// Pass 3: bf16 GEMM, out[M, DOUT] = Xaug @ Waug^T + b.
// BM=256 BN=128 BK=64, 512 threads = 8 waves (4 wm x 2 wn), per-wave 64x64
// output (acc[4][4] of 16x16x32 MFMA). 3-slot LDS ring, prefetch distance 2:
//   iter t: issue tile t+2 -> slot (t+2)%3  [slot freed end of iter t-1]
//           compute tile t from slot t%3    [landing gated by prev vmcnt(6)]
//           s_waitcnt vmcnt(6); s_barrier   [tile t+1 landed; t+2 in flight]
// Loads get ~2 K-tiles of MFMA (~2500 cyc) to cover ~900 cyc HBM latency.
// ---------------------------------------------------------------------------
__global__ __launch_bounds__(512, 2) void gemm_aug(
    const unsigned short* __restrict__ Xa, const unsigned short* __restrict__ Wa,
    const float* __restrict__ bias, float* __restrict__ out)
{
  __shared__ unsigned short lds_a[3 * ASLOT];  // 96 KB
  __shared__ unsigned short lds_b[3 * BSLOT];  // 48 KB

  const int tid = threadIdx.x;
  // T1: bijective XCD swizzle (1024 wgs % 8 == 0): each XCD gets 128
  // consecutive linear ids = 8 full bm-groups of 16 bn-blocks sharing A panels.
  const int lin = ((int)blockIdx.x & 7) * 128 + ((int)blockIdx.x >> 3);
  const int bn = lin & 15, bm = lin >> 4;
  const int w = tid >> 6, lane = tid & 63;
  const int wm = w >> 1, wn = w & 1;          // 4x2 wave grid, 64x64 each
  const int quad = lane >> 4, m16 = lane & 15;

  f32x4 acc[4][4];
  #pragma unroll
  for (int i = 0; i < 4; ++i)
    #pragma unroll
    for (int j = 0; j < 4; ++j) acc[i][j] = f32x4{0.f, 0.f, 0.f, 0.f};

  const unsigned short* ga = Xa + (size_t)bm * 256 * KA;
  const unsigned short* gb = Wa + (size_t)bn * 128 * KA;

  // staging descriptors: thread covers 16B chunk p = l*512 + tid of each tile
  int goa[4], loa[4], gob[2], lob[2];
  #pragma unroll
  for (int l = 0; l < 4; ++l) {
    int p = l * 512 + tid;
    int r = p >> 3;                     // A tile row 0..255
    int c = (p & 7) ^ (r & 7);          // swizzled global chunk
    goa[l] = r * KA + c * 8;            // ushort offset (+k0 later)
    loa[l] = (l * 512 + (tid & ~63)) * 8;  // wave-uniform LDS base (ushorts)
  }
  #pragma unroll
  for (int l = 0; l < 2; ++l) {
    int p = l * 512 + tid;
    int r = p >> 3;                     // B tile row 0..127
    int c = (p & 7) ^ (r & 7);
    gob[l] = r * KA + c * 8;
    lob[l] = (l * 512 + (tid & ~63)) * 8;
  }

  // prologue: tiles 0 and 1 into slots 0,1; wait for tile 0 (first 6 loads)
  stage_tile(ga, gb, lds_a, lds_b, 0, goa, loa, gob, lob);
  stage_tile(ga, gb, lds_a + ASLOT, lds_b + BSLOT, 64, goa, loa, gob, lob);
  asm volatile("s_waitcnt vmcnt(6)" ::: "memory");
  __builtin_amdgcn_s_barrier();
  __builtin_amdgcn_sched_barrier(0);

  int cs = 0;
  for (int t = 0; t < NT; ++t) {
    int ss = cs + 2; if (ss >= 3) ss -= 3;
    if (t + 2 < NT)
      stage_tile(ga, gb, lds_a + ss * ASLOT, lds_b + ss * BSLOT, (t + 2) * 64,
                 goa, loa, gob, lob);

    const unsigned short* sa = lds_a + cs * ASLOT;
    const unsigned short* sb = lds_b + cs * BSLOT;
    #pragma unroll
    for (int s = 0; s < 2; ++s) {
      const int cc = ((s * 4 + quad) ^ (m16 & 7)) * 8;  // swizzled k-chunk
      bf16x8 af[4], bfg[4];
      #pragma unroll
      for (int i = 0; i < 4; ++i)
        af[i] = *(const bf16x8*)(sa + (wm * 64 + i * 16 + m16) * 64 + cc);
      #pragma unroll
      for (int j = 0; j < 4; ++j)
        bfg[j] = *(const bf16x8*)(sb + (wn * 64 + j * 16 + m16) * 64 + cc);
      __builtin_amdgcn_s_setprio(1);
      #pragma unroll
      for (int i = 0; i < 4; ++i)
        #pragma unroll
        for (int j = 0; j < 4; ++j)
          acc[i][j] = __builtin_amdgcn_mfma_f32_16x16x32_bf16(af[i], bfg[j],
                                                              acc[i][j], 0, 0, 0);
      __builtin_amdgcn_s_setprio(0);
    }

    // gate: tile t+1 fully landed (only tile t+2's 6 loads may remain);
    // barrier: all waves' reads of slot (t%3) done before anyone overwrites it
    if (t + 2 < NT) asm volatile("s_waitcnt vmcnt(6)" ::: "memory");
    else            asm volatile("s_waitcnt vmcnt(0)" ::: "memory");
    __builtin_amdgcn_s_barrier();
    __builtin_amdgcn_sched_barrier(0);
    cs += 1; if (cs >= 3) cs -= 3;
  }

  // Epilogue: C/D layout col = lane&15, row = quad*4 + reg
  float bv[4];
  #pragma unroll
  for (int j = 0; j < 4; ++j) bv[j] = bias[bn * 128 + wn * 64 + j * 16 + m16];
  #pragma unroll
  for (int i = 0; i < 4; ++i) {
    const int row0 = bm * 256 + wm * 64 + i * 16 + quad * 4;
    #pragma unroll
    for (int j = 0; j < 4; ++j) {
      const int col = bn * 128 + wn * 64 + j * 16 + m16;
      #pragma unroll
      for (int r = 0; r < 4; ++r)
        out[(size_t)(row0 + r) * DOUT + col] = acc[i][j][r] + bv[j];
    }
  }
}

// ---------------------------------------------------------------------------
extern "C" void kernel_launch(void* const* d_in, const int* in_sizes, int n_in,
                              void* d_out, int out_size, void* d_ws, size_t ws_size,
                              hipStream_t stream) {
  const float* x    = (const float*)d_in[0];  // [4,4096,2048]
  const float* mask = (const float*)d_in[1];  // [4,4,4096,1]
  const float* W    = (const float*)d_in[2];  // [2048,2048]
  const float* bias = (const float*)d_in[3];  // [2048]
  const float* A    = (const float*)d_in[4];  // [4,16,2048] -> flat [64,2048]
  const float* Bw   = (const float*)d_in[5];  // [4,2048,16]
  float* out = (float*)d_out;

  // workspace layout:
  //   Xaug  [16384,2112] bf16 = 69,206,016 B
  //   Waug  [ 2048,2112] bf16 =  8,650,752 B
  //   Hpart [4,16384,64] f32  = 16,777,216 B
  // total = 94,633,984 bytes of d_ws
  unsigned short* Xaug = (unsigned short*)d_ws;
  unsigned short* Waug = Xaug + (size_t)M * KA;
  float* Hpart = (float*)(Waug + (size_t)DOUT * KA);

  pass1a_conv_hpart<<<dim3(M / 64 * KSPLIT), dim3(256), 0, stream>>>(x, A, Xaug, Hpart);
  pass1b_reduce_mask<<<dim3(M * 64 / 256), dim3(256), 0, stream>>>(Hpart, mask, Xaug);
  pass2_wcvt<<<dim3((DOUT * (DIN / 8)) / 256), dim3(256), 0, stream>>>(W, Bw, Waug);
  gemm_aug<<<dim3(1024), dim3(512), 0, stream>>>(Xaug, Waug, bias, out);
}

// Round 3
// 456.461 us; speedup vs baseline: 1.0207x; 1.0207x over previous
//
#include <hip/hip_runtime.h>
#include <stdint.h>

// ContextPeftAdaptorLora on MI355X.
// Strategy: fold the 4 rank-16 LoRA adaptors into the K dimension of the base
// GEMM:  out = [x | mask*H] @ [W | 2*Bw]^T + b   with K' = 2048 + 64 = 2112.
// Pass1a: convert x->bf16 into Xaug AND compute PARTIAL H = x @ A^T (MFMA),
//         K split 4 ways -> 1024 blocks (4/CU).
// Pass1b: reduce the 4 partials, apply per-adaptor mask, write Xaug H cols.
// Pass2:  convert W->bf16 and scaled Bw into Waug.
// Pass3:  256x256 8-wave GEMM, per-wave 128x64 output (43.7 FLOP/LDS-byte so
//         LDS b128 BW no longer binds, unlike 64x64-wave structures at 32).
//         K-step = 4 phases (kk-half x i-half); 8 half-tile LDS buffers
//         (2dbuf x {A,B} x 2 K-halves, 128 KiB); ONE half-tile staged per
//         phase, consumed 4-5 phases later; vmcnt(6) gates before the q1/q3
//         barriers (never vmcnt(0) in steady state). T2 XOR chunk swizzle on
//         the global source side (0 conflicts measured), T5 setprio, T1 XCD
//         swizzle.

typedef __attribute__((ext_vector_type(8))) short bf16x8;   // 8 bf16 = 4 VGPR
typedef __attribute__((ext_vector_type(4))) float f32x4;    // MFMA C/D
typedef __attribute__((ext_vector_type(4))) unsigned short u16x4;
typedef __attribute__((ext_vector_type(8))) unsigned short u16x8;

#define GAS __attribute__((address_space(1)))
#define LAS __attribute__((address_space(3)))

static constexpr int BB   = 4;
static constexpr int SS   = 4096;
static constexpr int DIN  = 2048;
static constexpr int DOUT = 2048;
static constexpr int NADP = 4;
static constexpr int RR   = 16;
static constexpr int M    = BB * SS;          // 16384 rows
static constexpr int KA   = DIN + NADP * RR;  // 2112 augmented K
static constexpr float SCALE = 2.0f;          // lora_alpha / r

static constexpr int KSPLIT = 4;              // H K-reduction split factor
static constexpr int KCH    = DIN / KSPLIT;   // 512 K per block

static constexpr int NT  = KA / 64;           // 33 K-steps in the GEMM
static constexpr int HTS = 256 * 32;          // ushorts per half-tile (16 KB)

static_assert(KA % 64 == 0, "K-loop needs BK=64 divisibility");
static_assert(NT >= 3, "tail specialization assumes >=3 K-steps");

__device__ __forceinline__ unsigned short f2bf(float f) {
  union { float f; uint32_t u; } v; v.f = f;
  uint32_t u = v.u;
  // round-to-nearest-even
  return (unsigned short)((u + 0x7FFFu + ((u >> 16) & 1u)) >> 16);
}

// ---------------------------------------------------------------------------
// Pass 1a: rows in blocks of 64, K in blocks of 512 (KSPLIT=4). Streams its
// x panel once: converts to bf16 (written to Xaug cols [kBase,kBase+512)) and
// accumulates partial H = x @ A_flat^T over its K slice via 16x16x32 bf16
// MFMA on staged LDS chunks. Epilogue writes f32 partials to Hpart[ks][M][64].
// ---------------------------------------------------------------------------
__global__ __launch_bounds__(256) void pass1a_conv_hpart(
    const float* __restrict__ x, const float* __restrict__ A,
    unsigned short* __restrict__ Xaug, float* __restrict__ Hpart)
{
  __shared__ unsigned short xb[64 * 64];  // [row][k] bf16, 8 KB
  __shared__ unsigned short ab[64 * 64];  // [j][k]   bf16, 8 KB

  const int tid = threadIdx.x;
  const int rb = blockIdx.x >> 2;         // 0..255 row-block
  const int ks = blockIdx.x & 3;          // 0..3   K-slice
  const int rowBase = rb * 64;
  const int kBase = ks * KCH;
  const int w = tid >> 6, lane = tid & 63;
  const int quad = lane >> 4, m16 = lane & 15;

  f32x4 acc[4];
  #pragma unroll
  for (int j = 0; j < 4; ++j) acc[j] = f32x4{0.f, 0.f, 0.f, 0.f};

  for (int kc = kBase; kc < kBase + KCH; kc += 64) {
    __syncthreads();  // protect LDS against overwrite while prior MFMA reads run
    #pragma unroll
    for (int l = 0; l < 4; ++l) {
      int v = l * 256 + tid;        // float4-chunk id, 0..1023
      int r = v >> 4;               // row (0..63)
      int k = (v & 15) * 4;         // k offset (0..60)
      float4 xv = *(const float4*)(x + (size_t)(rowBase + r) * DIN + kc + k);
      u16x4 xq = { f2bf(xv.x), f2bf(xv.y), f2bf(xv.z), f2bf(xv.w) };
      *(u16x4*)(xb + r * 64 + k) = xq;
      *(u16x4*)(Xaug + (size_t)(rowBase + r) * KA + kc + k) = xq;
      float4 av = *(const float4*)(A + (size_t)r * DIN + kc + k);  // j = r
      u16x4 aq = { f2bf(av.x), f2bf(av.y), f2bf(av.z), f2bf(av.w) };
      *(u16x4*)(ab + r * 64 + k) = aq;
    }
    __syncthreads();
    // wave w computes H rows [w*16, w*16+16) x all 64 j
    #pragma unroll
    for (int s = 0; s < 2; ++s) {
      bf16x8 af = *(const bf16x8*)(xb + (w * 16 + m16) * 64 + s * 32 + quad * 8);
      #pragma unroll
      for (int jt = 0; jt < 4; ++jt) {
        bf16x8 bfg = *(const bf16x8*)(ab + (jt * 16 + m16) * 64 + s * 32 + quad * 8);
        acc[jt] = __builtin_amdgcn_mfma_f32_16x16x32_bf16(af, bfg, acc[jt], 0, 0, 0);
      }
    }
  }

  // Epilogue: Hpart[ks][row][j] = partial H over this K slice.
  // C/D layout: col = lane&15, row = quad*4 + reg  [m89/m91 verified]
  const int grow0 = rowBase + w * 16 + quad * 4;
  #pragma unroll
  for (int jt = 0; jt < 4; ++jt) {
    #pragma unroll
    for (int r = 0; r < 4; ++r) {
      int grow = grow0 + r;
      Hpart[(((size_t)ks * M + grow) << 6) + jt * 16 + m16] = acc[jt][r];
    }
  }
}

// ---------------------------------------------------------------------------
// Pass 1b: H[row,j] = sum_ks Hpart[ks][row][j]; apply mask[n=j/16, row];
// write bf16 into Xaug cols [2048, 2112). ~17 MB read, 2 MB write.
// ---------------------------------------------------------------------------
__global__ __launch_bounds__(256) void pass1b_reduce_mask(
    const float* __restrict__ Hpart, const float* __restrict__ mask,
    unsigned short* __restrict__ Xaug)
{
  const int idx = blockIdx.x * 256 + threadIdx.x;  // 0 .. M*64-1
  const int row = idx >> 6;
  const int j   = idx & 63;
  float s = 0.f;
  #pragma unroll
  for (int ks = 0; ks < KSPLIT; ++ks)
    s += Hpart[(((size_t)ks * M) << 6) + idx];
  s *= mask[(size_t)(j >> 4) * M + row];
  Xaug[(size_t)row * KA + DIN + j] = f2bf(s);
}

// ---------------------------------------------------------------------------
// Pass 2: Waug[col, 0:2048) = bf16(W[col,:]);  Waug[col, 2048+n*16+r] =
// bf16(SCALE * Bw[n, col, r]).
// ---------------------------------------------------------------------------
__global__ __launch_bounds__(256) void pass2_wcvt(
    const float* __restrict__ W, const float* __restrict__ Bw,
    unsigned short* __restrict__ Waug)
{
  const int idx = blockIdx.x * 256 + threadIdx.x;  // 0..524287
  const int row = idx >> 8;          // 2048 rows, 256 8-elem chunks each
  const int k   = (idx & 255) * 8;
  float4 a = *(const float4*)(W + (size_t)row * DIN + k);
  float4 b = *(const float4*)(W + (size_t)row * DIN + k + 4);
  u16x8 q = { f2bf(a.x), f2bf(a.y), f2bf(a.z), f2bf(a.w),
              f2bf(b.x), f2bf(b.y), f2bf(b.z), f2bf(b.w) };
  *(u16x8*)(Waug + (size_t)row * KA + k) = q;

  if (idx < DOUT * NADP) {           // 8192 threads build the Bwcat columns
    const int col = idx >> 2, n = idx & 3;
    const float* src = Bw + (size_t)n * DOUT * RR + (size_t)col * RR;
    #pragma unroll
    for (int t = 0; t < 4; ++t) {
      float4 bv = *(const float4*)(src + 4 * t);
      u16x4 qq = { f2bf(SCALE * bv.x), f2bf(SCALE * bv.y),
                   f2bf(SCALE * bv.z), f2bf(SCALE * bv.w) };
      *(u16x4*)(Waug + (size_t)col * KA + DIN + n * 16 + 4 * t) = qq;
    }
  }
}

// ---------------------------------------------------------------------------
// GEMM helpers.
// ---------------------------------------------------------------------------
struct Stg { int so0, so1, do0, do1; };  // per-thread stage offsets (ushorts)

__device__ __forceinline__ void phase_barrier() {
  __builtin_amdgcn_sched_barrier(0);
  __builtin_amdgcn_s_barrier();
  __builtin_amdgcn_sched_barrier(0);
}

// Stage one half-tile (256 rows x 32 K bf16 = 16 KB) via 2 global_load_lds
// width=16 per thread. LDS dest linear (wave-uniform base + lane*16); chunk
// XOR swizzle (LDS chunk (r,cl) holds global (r, cl^(r&3))) applied on the
// GLOBAL source address. koff = k start in ushorts.
__device__ __forceinline__ void stage_half(
    const unsigned short* __restrict__ g, unsigned short* l, int koff,
    const Stg& s)
{
  __builtin_amdgcn_global_load_lds((const GAS void*)(g + s.so0 + koff),
                                   (LAS void*)(l + s.do0), 16, 0, 0);
  __builtin_amdgcn_global_load_lds((const GAS void*)(g + s.so1 + koff),
                                   (LAS void*)(l + s.do1), 16, 0, 0);
}

// One K-step (BK=64) = 4 phases q0..q3 = (kk-half, i-half). Stage schedule
// (derived; retire-order checked): q0: B-kh0(t+1), q1: A-kh1(t+1),
// q2: B-kh1(t+1), q3: A-kh0(t+2) [into the CURRENT parity's kh0 buffer,
// whose reads finished at the q1 barrier]. Gates: vmcnt(6) before the q1 and
// q3 barriers retire exactly through the half-tiles needed by the next two
// phases (3 stages x 2 loads stay in flight). Tail: VM3=4 at t=NT-2 (q3
// stage skipped), VM1=0 at t=NT-1 (no stages left).
template<int VM1, int VM3, bool S0, bool S1, bool S2, bool S3>
__device__ __forceinline__ void kstep(int t,
    const unsigned short* __restrict__ ga, const unsigned short* __restrict__ gb,
    unsigned short* la, unsigned short* lb, const Stg& st,
    int rowA, int rowB, f32x4 (&acc)[8][4])
{
  const int cb = (t & 1) * (2 * HTS);
  const int nb = cb ^ (2 * HTS);
  const unsigned short* A0 = la + cb;   // A kh0, current K-step
  const unsigned short* B0 = lb + cb;
  const unsigned short* A1 = A0 + HTS;  // A kh1
  const unsigned short* B1 = B0 + HTS;
  bf16x8 af[4], bfg[4];

  // ---- q0: kk=0, i-half 0 ----
  if (S0) stage_half(gb, lb + nb, (t + 1) * 64, st);
  #pragma unroll
  for (int j = 0; j < 4; ++j) bfg[j] = *(const bf16x8*)(B0 + rowB + j * 512);
  #pragma unroll
  for (int ii = 0; ii < 4; ++ii) af[ii] = *(const bf16x8*)(A0 + rowA + ii * 512);
  __builtin_amdgcn_s_setprio(1);
  #pragma unroll
  for (int ii = 0; ii < 4; ++ii)
    #pragma unroll
    for (int j = 0; j < 4; ++j)
      acc[ii][j] = __builtin_amdgcn_mfma_f32_16x16x32_bf16(af[ii], bfg[j],
                                                           acc[ii][j], 0, 0, 0);
  __builtin_amdgcn_s_setprio(0);
  phase_barrier();

  // ---- q1: kk=0, i-half 1 (bfg reused) ----
  if (S1) stage_half(ga, la + nb + HTS, (t + 1) * 64 + 32, st);
  #pragma unroll
  for (int ii = 0; ii < 4; ++ii)
    af[ii] = *(const bf16x8*)(A0 + rowA + 2048 + ii * 512);
  __builtin_amdgcn_s_setprio(1);
  #pragma unroll
  for (int ii = 0; ii < 4; ++ii)
    #pragma unroll
    for (int j = 0; j < 4; ++j)
      acc[4 + ii][j] = __builtin_amdgcn_mfma_f32_16x16x32_bf16(af[ii], bfg[j],
                                                               acc[4 + ii][j], 0, 0, 0);
  __builtin_amdgcn_s_setprio(0);
  if constexpr (VM1 >= 0)
    asm volatile("s_waitcnt vmcnt(%0)" :: "i"(VM1) : "memory");
  phase_barrier();

  // ---- q2: kk=1, i-half 0 ----
  if (S2) stage_half(gb, lb + nb + HTS, (t + 1) * 64 + 32, st);
  #pragma unroll
  for (int j = 0; j < 4; ++j) bfg[j] = *(const bf16x8*)(B1 + rowB + j * 512);
  #pragma unroll
  for (int ii = 0; ii < 4; ++ii) af[ii] = *(const bf16x8*)(A1 + rowA + ii * 512);
  __builtin_amdgcn_s_setprio(1);
  #pragma unroll
  for (int ii = 0; ii < 4; ++ii)
    #pragma unroll
    for (int j = 0; j < 4; ++j)
      acc[ii][j] = __builtin_amdgcn_mfma_f32_16x16x32_bf16(af[ii], bfg[j],
                                                           acc[ii][j], 0, 0, 0);
  __builtin_amdgcn_s_setprio(0);
  phase_barrier();

  // ---- q3: kk=1, i-half 1 ----
  if (S3) stage_half(ga, la + cb, (t + 2) * 64, st);  // reads of this buffer
                                                      // ended at the q1 barrier
  #pragma unroll
  for (int ii = 0; ii < 4; ++ii)
    af[ii] = *(const bf16x8*)(A1 + rowA + 2048 + ii * 512);
  __builtin_amdgcn_s_setprio(1);
  #pragma unroll
  for (int ii = 0; ii < 4; ++ii)
    #pragma unroll
    for (int j = 0; j < 4; ++j)
      acc[4 + ii][j] = __builtin_amdgcn_mfma_f32_16x16x32_bf16(af[ii], bfg[j],
                                                               acc[4 + ii][j], 0, 0, 0);
  __builtin_amdgcn_s_setprio(0);
  if constexpr (VM3 >= 0)
    asm volatile("s_waitcnt vmcnt(%0)" :: "i"(VM3) : "memory");
  phase_barrier();
}

// ---------------------------------------------------------------------------
// Pass 3: bf16 GEMM, out[M, DOUT] = Xaug @ Waug^T + b.
// BM=BN=256, BK=64, 512 threads = 8 waves (2 wm x 4 wn), per-wave 128x64.
// LDS: [2 parity][2 kh][256 rows][4 chunks] per operand = 64 KB x2 = 128 KB.
// ---------------------------------------------------------------------------
__global__ __launch_bounds__(512, 2) void gemm_aug(
    const unsigned short* __restrict__ Xa, const unsigned short* __restrict__ Wa,
    const float* __restrict__ bias, float* __restrict__ out)
{
  __shared__ unsigned short lds_a[4 * HTS];  // 64 KB
  __shared__ unsigned short lds_b[4 * HTS];  // 64 KB

  const int tid = threadIdx.x;
  // T1: bijective XCD swizzle (512 wgs % 8 == 0). XCD x gets bm in
  // [x*8, x*8+8) x all 8 bn (bn fastest -> B panels reused across bm rows).
  const int lin = ((int)blockIdx.x & 7) * 64 + ((int)blockIdx.x >> 3);
  const int bm = lin >> 3, bn = lin & 7;
  const int w = tid >> 6, lane = tid & 63;
  const int wm = w >> 2, wn = w & 3;          // 2x4 wave grid, 128x64 each
  const int quad = lane >> 4, m16 = lane & 15;

  f32x4 acc[8][4];
  #pragma unroll
  for (int i = 0; i < 8; ++i)
    #pragma unroll
    for (int j = 0; j < 4; ++j) acc[i][j] = f32x4{0.f, 0.f, 0.f, 0.f};

  const unsigned short* ga = Xa + (size_t)bm * 256 * KA;
  const unsigned short* gb = Wa + (size_t)bn * 256 * KA;

  // staging offsets: thread covers 16B chunks p = tid and p = 512+tid of each
  // half-tile (256 rows x 4 chunks). Global chunk c = (p&3)^(r&3) (swizzle).
  Stg st;
  {
    int p0 = tid, r0 = p0 >> 2, c0 = (p0 & 3) ^ (r0 & 3);
    int p1 = 512 + tid, r1 = p1 >> 2, c1 = (p1 & 3) ^ (r1 & 3);
    st.so0 = r0 * KA + c0 * 8;
    st.so1 = r1 * KA + c1 * 8;
    st.do0 = (tid & ~63) * 8;            // wave-uniform LDS base, chunk p0
    st.do1 = (512 + (tid & ~63)) * 8;    // chunk p1
  }

  // fragment read bases: row-swizzled chunk = quad ^ (row&3), row&3 == m16&3
  const int cswz = (quad ^ (m16 & 3)) * 8;
  const int rowA = (wm * 128 + m16) * 32 + cswz;  // +ih*2048 +ii*512
  const int rowB = (wn * 64 + m16) * 32 + cswz;   // +j*512

  // prologue: 5 half-tiles in schedule order; vmcnt(6) retires the 2 oldest
  // (A-kh0(0), B-kh0(0)) needed by q0 of t=0.
  stage_half(ga, lds_a, 0, st);              // A-kh0(0)
  stage_half(gb, lds_b, 0, st);              // B-kh0(0)
  stage_half(ga, lds_a + HTS, 32, st);       // A-kh1(0)
  stage_half(gb, lds_b + HTS, 32, st);       // B-kh1(0)
  stage_half(ga, lds_a + 2 * HTS, 64, st);   // A-kh0(1) -> parity 1, kh0
  asm volatile("s_waitcnt vmcnt(6)" ::: "memory");
  phase_barrier();

  for (int t = 0; t < NT - 2; ++t)
    kstep<6, 6, true, true, true, true>(t, ga, gb, lds_a, lds_b, st, rowA, rowB, acc);
  kstep<6, 4, true, true, true, false>(NT - 2, ga, gb, lds_a, lds_b, st, rowA, rowB, acc);
  kstep<0, -1, false, false, false, false>(NT - 1, ga, gb, lds_a, lds_b, st, rowA, rowB, acc);

  // Epilogue: C/D layout col = lane&15, row = quad*4 + reg
  float bv[4];
  #pragma unroll
  for (int j = 0; j < 4; ++j) bv[j] = bias[bn * 256 + wn * 64 + j * 16 + m16];
  #pragma unroll
  for (int i = 0; i < 8; ++i) {
    const int row0 = bm * 256 + wm * 128 + i * 16 + quad * 4;
    #pragma unroll
    for (int j = 0; j < 4; ++j) {
      const int col = bn * 256 + wn * 64 + j * 16 + m16;
      #pragma unroll
      for (int r = 0; r < 4; ++r)
        out[(size_t)(row0 + r) * DOUT + col] = acc[i][j][r] + bv[j];
    }
  }
}

// ---------------------------------------------------------------------------
extern "C" void kernel_launch(void* const* d_in, const int* in_sizes, int n_in,
                              void* d_out, int out_size, void* d_ws, size_t ws_size,
                              hipStream_t stream) {
  const float* x    = (const float*)d_in[0];  // [4,4096,2048]
  const float* mask = (const float*)d_in[1];  // [4,4,4096,1]
  const float* W    = (const float*)d_in[2];  // [2048,2048]
  const float* bias = (const float*)d_in[3];  // [2048]
  const float* A    = (const float*)d_in[4];  // [4,16,2048] -> flat [64,2048]
  const float* Bw   = (const float*)d_in[5];  // [4,2048,16]
  float* out = (float*)d_out;

  // workspace layout:
  //   Xaug  [16384,2112] bf16 = 69,206,016 B
  //   Waug  [ 2048,2112] bf16 =  8,650,752 B
  //   Hpart [4,16384,64] f32  = 16,777,216 B
  // total = 94,633,984 bytes of d_ws
  unsigned short* Xaug = (unsigned short*)d_ws;
  unsigned short* Waug = Xaug + (size_t)M * KA;
  float* Hpart = (float*)(Waug + (size_t)DOUT * KA);

  pass1a_conv_hpart<<<dim3(M / 64 * KSPLIT), dim3(256), 0, stream>>>(x, A, Xaug, Hpart);
  pass1b_reduce_mask<<<dim3(M * 64 / 256), dim3(256), 0, stream>>>(Hpart, mask, Xaug);
  pass2_wcvt<<<dim3((DOUT * (DIN / 8)) / 256), dim3(256), 0, stream>>>(W, Bw, Waug);
  gemm_aug<<<dim3(512), dim3(512), 0, stream>>>(Xaug, Waug, bias, out);
}

// Round 4
// 428.326 us; speedup vs baseline: 1.0877x; 1.0657x over previous
//
#include <hip/hip_runtime.h>
#include <stdint.h>

// ContextPeftAdaptorLora on MI355X.
// Strategy: fold the 4 rank-16 LoRA adaptors into the K dimension of the base
// GEMM:  out = [x | mask*H] @ [W | 2*Bw]^T + b   with K' = 2048 + 64 = 2112.
// Pass1a: convert x->bf16 into Xaug AND compute PARTIAL H = x @ A^T (MFMA),
//         K split 4 ways -> 1024 blocks (4/CU).
// Pass1b: reduce the 4 partials, apply per-adaptor mask, write Xaug H cols.
// Pass2:  convert W->bf16 and scaled Bw into Waug.
// Pass3:  256x256 8-wave GEMM, per-wave 128x64 output INTERLEAVED across
//         M/N-half-tiles (rows ih*128+wm*64+.., cols jh*128+wn*32+..) so each
//         C-quadrant phase consumes exactly one A-half + one B-half ->
//         genuine staggered pipeline. Half-tiles are [128 rows][64 K] bf16
//         (128-B rows, 8-chunk XOR swizzle = the measured-0-conflict layout).
//         2 regions/K-step, 2 barriers/K-step, counted gates G1=vmcnt(6),
//         G3=vmcnt(2) (never vmcnt(0) in steady state); every stage gets
//         >= 1 region (~1240cy MFMA) before its gate. T5 setprio, T1 XCD
//         swizzle.

typedef __attribute__((ext_vector_type(8))) short bf16x8;   // 8 bf16 = 4 VGPR
typedef __attribute__((ext_vector_type(4))) float f32x4;    // MFMA C/D
typedef __attribute__((ext_vector_type(4))) unsigned short u16x4;
typedef __attribute__((ext_vector_type(8))) unsigned short u16x8;

#define GAS __attribute__((address_space(1)))
#define LAS __attribute__((address_space(3)))

static constexpr int BB   = 4;
static constexpr int SS   = 4096;
static constexpr int DIN  = 2048;
static constexpr int DOUT = 2048;
static constexpr int NADP = 4;
static constexpr int RR   = 16;
static constexpr int M    = BB * SS;          // 16384 rows
static constexpr int KA   = DIN + NADP * RR;  // 2112 augmented K
static constexpr float SCALE = 2.0f;          // lora_alpha / r

static constexpr int KSPLIT = 4;              // H K-reduction split factor
static constexpr int KCH    = DIN / KSPLIT;   // 512 K per block

static constexpr int NT = KA / 64;            // 33 K-steps in the GEMM
static constexpr int HT = 128 * 64;           // ushorts per half-tile (16 KB)

static_assert(KA % 64 == 0, "K-loop needs BK=64 divisibility");
static_assert(NT >= 2, "pipeline needs >=2 K-steps");

__device__ __forceinline__ unsigned short f2bf(float f) {
  union { float f; uint32_t u; } v; v.f = f;
  uint32_t u = v.u;
  // round-to-nearest-even
  return (unsigned short)((u + 0x7FFFu + ((u >> 16) & 1u)) >> 16);
}

// ---------------------------------------------------------------------------
// Pass 1a: rows in blocks of 64, K in blocks of 512 (KSPLIT=4). Streams its
// x panel once: converts to bf16 (written to Xaug cols [kBase,kBase+512)) and
// accumulates partial H = x @ A_flat^T over its K slice via 16x16x32 bf16
// MFMA on staged LDS chunks. Epilogue writes f32 partials to Hpart[ks][M][64].
// ---------------------------------------------------------------------------
__global__ __launch_bounds__(256) void pass1a_conv_hpart(
    const float* __restrict__ x, const float* __restrict__ A,
    unsigned short* __restrict__ Xaug, float* __restrict__ Hpart)
{
  __shared__ unsigned short xb[64 * 64];  // [row][k] bf16, 8 KB
  __shared__ unsigned short ab[64 * 64];  // [j][k]   bf16, 8 KB

  const int tid = threadIdx.x;
  const int rb = blockIdx.x >> 2;         // 0..255 row-block
  const int ks = blockIdx.x & 3;          // 0..3   K-slice
  const int rowBase = rb * 64;
  const int kBase = ks * KCH;
  const int w = tid >> 6, lane = tid & 63;
  const int quad = lane >> 4, m16 = lane & 15;

  f32x4 acc[4];
  #pragma unroll
  for (int j = 0; j < 4; ++j) acc[j] = f32x4{0.f, 0.f, 0.f, 0.f};

  for (int kc = kBase; kc < kBase + KCH; kc += 64) {
    __syncthreads();  // protect LDS against overwrite while prior MFMA reads run
    #pragma unroll
    for (int l = 0; l < 4; ++l) {
      int v = l * 256 + tid;        // float4-chunk id, 0..1023
      int r = v >> 4;               // row (0..63)
      int k = (v & 15) * 4;         // k offset (0..60)
      float4 xv = *(const float4*)(x + (size_t)(rowBase + r) * DIN + kc + k);
      u16x4 xq = { f2bf(xv.x), f2bf(xv.y), f2bf(xv.z), f2bf(xv.w) };
      *(u16x4*)(xb + r * 64 + k) = xq;
      *(u16x4*)(Xaug + (size_t)(rowBase + r) * KA + kc + k) = xq;
      float4 av = *(const float4*)(A + (size_t)r * DIN + kc + k);  // j = r
      u16x4 aq = { f2bf(av.x), f2bf(av.y), f2bf(av.z), f2bf(av.w) };
      *(u16x4*)(ab + r * 64 + k) = aq;
    }
    __syncthreads();
    // wave w computes H rows [w*16, w*16+16) x all 64 j
    #pragma unroll
    for (int s = 0; s < 2; ++s) {
      bf16x8 af = *(const bf16x8*)(xb + (w * 16 + m16) * 64 + s * 32 + quad * 8);
      #pragma unroll
      for (int jt = 0; jt < 4; ++jt) {
        bf16x8 bfg = *(const bf16x8*)(ab + (jt * 16 + m16) * 64 + s * 32 + quad * 8);
        acc[jt] = __builtin_amdgcn_mfma_f32_16x16x32_bf16(af, bfg, acc[jt], 0, 0, 0);
      }
    }
  }

  // Epilogue: Hpart[ks][row][j] = partial H over this K slice.
  // C/D layout: col = lane&15, row = quad*4 + reg  [m89/m91 verified]
  const int grow0 = rowBase + w * 16 + quad * 4;
  #pragma unroll
  for (int jt = 0; jt < 4; ++jt) {
    #pragma unroll
    for (int r = 0; r < 4; ++r) {
      int grow = grow0 + r;
      Hpart[(((size_t)ks * M + grow) << 6) + jt * 16 + m16] = acc[jt][r];
    }
  }
}

// ---------------------------------------------------------------------------
// Pass 1b: H[row,j] = sum_ks Hpart[ks][row][j]; apply mask[n=j/16, row];
// write bf16 into Xaug cols [2048, 2112). ~17 MB read, 2 MB write.
// ---------------------------------------------------------------------------
__global__ __launch_bounds__(256) void pass1b_reduce_mask(
    const float* __restrict__ Hpart, const float* __restrict__ mask,
    unsigned short* __restrict__ Xaug)
{
  const int idx = blockIdx.x * 256 + threadIdx.x;  // 0 .. M*64-1
  const int row = idx >> 6;
  const int j   = idx & 63;
  float s = 0.f;
  #pragma unroll
  for (int ks = 0; ks < KSPLIT; ++ks)
    s += Hpart[(((size_t)ks * M) << 6) + idx];
  s *= mask[(size_t)(j >> 4) * M + row];
  Xaug[(size_t)row * KA + DIN + j] = f2bf(s);
}

// ---------------------------------------------------------------------------
// Pass 2: Waug[col, 0:2048) = bf16(W[col,:]);  Waug[col, 2048+n*16+r] =
// bf16(SCALE * Bw[n, col, r]).
// ---------------------------------------------------------------------------
__global__ __launch_bounds__(256) void pass2_wcvt(
    const float* __restrict__ W, const float* __restrict__ Bw,
    unsigned short* __restrict__ Waug)
{
  const int idx = blockIdx.x * 256 + threadIdx.x;  // 0..524287
  const int row = idx >> 8;          // 2048 rows, 256 8-elem chunks each
  const int k   = (idx & 255) * 8;
  float4 a = *(const float4*)(W + (size_t)row * DIN + k);
  float4 b = *(const float4*)(W + (size_t)row * DIN + k + 4);
  u16x8 q = { f2bf(a.x), f2bf(a.y), f2bf(a.z), f2bf(a.w),
              f2bf(b.x), f2bf(b.y), f2bf(b.z), f2bf(b.w) };
  *(u16x8*)(Waug + (size_t)row * KA + k) = q;

  if (idx < DOUT * NADP) {           // 8192 threads build the Bwcat columns
    const int col = idx >> 2, n = idx & 3;
    const float* src = Bw + (size_t)n * DOUT * RR + (size_t)col * RR;
    #pragma unroll
    for (int t = 0; t < 4; ++t) {
      float4 bv = *(const float4*)(src + 4 * t);
      u16x4 qq = { f2bf(SCALE * bv.x), f2bf(SCALE * bv.y),
                   f2bf(SCALE * bv.z), f2bf(SCALE * bv.w) };
      *(u16x4*)(Waug + (size_t)col * KA + DIN + n * 16 + 4 * t) = qq;
    }
  }
}

// ---------------------------------------------------------------------------
// GEMM helpers.
// ---------------------------------------------------------------------------
struct Stg { int so, dofs; };  // per-thread stage offsets (ushorts)

__device__ __forceinline__ void gate_barrier() {
  __builtin_amdgcn_sched_barrier(0);
  __builtin_amdgcn_s_barrier();
  __builtin_amdgcn_sched_barrier(0);
}

// Stage one half-tile (128 rows x 64 K bf16 = 16 KB) via 2 global_load_lds
// width=16 per thread (chunks tid and 512+tid). LDS dest linear (wave-uniform
// base + lane*16); chunk XOR swizzle (LDS chunk (r,cl) holds global chunk
// cl^(r&7)) applied on the GLOBAL source address. 2 vmcnt units per call.
__device__ __forceinline__ void stage_half(
    const unsigned short* __restrict__ g, unsigned short* l, int koff,
    const Stg& st)
{
  __builtin_amdgcn_global_load_lds((const GAS void*)(g + st.so + koff),
                                   (LAS void*)(l + st.dofs), 16, 0, 0);
  __builtin_amdgcn_global_load_lds((const GAS void*)(g + st.so + 64 * KA + koff),
                                   (LAS void*)(l + st.dofs + 4096), 16, 0, 0);
}

// One K-step (BK=64) = 2 regions, 4 C-quadrants (ih,jh).
//   R01: quadrants (0,0)+(0,1): 16 ds_read_b128 (af ih0, bA jh0, bB jh1),
//        32 MFMA; stages A-h0,B-h0,B-h1 of t+1; G1 = vmcnt(6) + barrier.
//   R23: quadrants (1,0)+(1,1): 8 ds_read (af ih1; bA/bB reused in regs),
//        32 MFMA; stages A-h1 of t+1; G3 = vmcnt(2) + barrier.
// Queue invariant entering step t: only A-h1(t) outstanding (2 units).
//   G1 retires A-h1(t) (needed by R23); G3 retires the three R01 stages
//   (needed by next R01). Last step: VM1=0, G3 skipped.
template<int VM1, int VM3, bool S>
__device__ __forceinline__ void kstep(int t,
    const unsigned short* __restrict__ ga, const unsigned short* __restrict__ gb,
    unsigned short* la, unsigned short* lb, const Stg& st,
    int rowA, int rowB, const int (&cc)[2], f32x4 (&acc)[8][4])
{
  const int cp = (t & 1) * (2 * HT);
  const int np = cp ^ (2 * HT);
  const unsigned short* A0 = la + cp;       // A ih=0, current step
  const unsigned short* A1 = la + cp + HT;  // A ih=1
  const unsigned short* B0 = lb + cp;       // B jh=0
  const unsigned short* B1 = lb + cp + HT;  // B jh=1
  bf16x8 af[4][2], bA[2][2], bB[2][2];

  // ---- R01 ----
  if (S) {
    stage_half(ga, la + np, (t + 1) * 64, st);                 // A-h0(t+1)
    stage_half(gb, lb + np, (t + 1) * 64, st);                 // B-h0(t+1)
    stage_half(gb + 128 * KA, lb + np + HT, (t + 1) * 64, st); // B-h1(t+1)
  }
  #pragma unroll
  for (int i = 0; i < 4; ++i)
    #pragma unroll
    for (int kk = 0; kk < 2; ++kk)
      af[i][kk] = *(const bf16x8*)(A0 + rowA + i * 1024 + cc[kk]);
  #pragma unroll
  for (int j = 0; j < 2; ++j)
    #pragma unroll
    for (int kk = 0; kk < 2; ++kk) {
      bA[j][kk] = *(const bf16x8*)(B0 + rowB + j * 1024 + cc[kk]);
      bB[j][kk] = *(const bf16x8*)(B1 + rowB + j * 1024 + cc[kk]);
    }
  __builtin_amdgcn_s_setprio(1);
  #pragma unroll
  for (int kk = 0; kk < 2; ++kk)
    #pragma unroll
    for (int i = 0; i < 4; ++i)
      #pragma unroll
      for (int j = 0; j < 2; ++j) {
        acc[i][j]     = __builtin_amdgcn_mfma_f32_16x16x32_bf16(af[i][kk], bA[j][kk], acc[i][j], 0, 0, 0);
        acc[i][2 + j] = __builtin_amdgcn_mfma_f32_16x16x32_bf16(af[i][kk], bB[j][kk], acc[i][2 + j], 0, 0, 0);
      }
  __builtin_amdgcn_s_setprio(0);
  asm volatile("s_waitcnt vmcnt(%0)" :: "i"(VM1) : "memory");
  gate_barrier();

  // ---- R23 ----
  if (S) stage_half(ga + 128 * KA, la + np + HT, (t + 1) * 64, st); // A-h1(t+1)
  #pragma unroll
  for (int i = 0; i < 4; ++i)
    #pragma unroll
    for (int kk = 0; kk < 2; ++kk)
      af[i][kk] = *(const bf16x8*)(A1 + rowA + i * 1024 + cc[kk]);
  __builtin_amdgcn_s_setprio(1);
  #pragma unroll
  for (int kk = 0; kk < 2; ++kk)
    #pragma unroll
    for (int i = 0; i < 4; ++i)
      #pragma unroll
      for (int j = 0; j < 2; ++j) {
        acc[4 + i][j]     = __builtin_amdgcn_mfma_f32_16x16x32_bf16(af[i][kk], bA[j][kk], acc[4 + i][j], 0, 0, 0);
        acc[4 + i][2 + j] = __builtin_amdgcn_mfma_f32_16x16x32_bf16(af[i][kk], bB[j][kk], acc[4 + i][2 + j], 0, 0, 0);
      }
  __builtin_amdgcn_s_setprio(0);
  if constexpr (VM3 >= 0) {
    asm volatile("s_waitcnt vmcnt(%0)" :: "i"(VM3) : "memory");
    gate_barrier();
  }
}

// ---------------------------------------------------------------------------
// Pass 3: bf16 GEMM, out[M, DOUT] = Xaug @ Waug^T + b.
// BM=BN=256, BK=64, 512 threads = 8 waves (2 wm x 4 wn). Wave output 128x64
// interleaved: rows ih*128 + wm*64 + i*16, cols jh*128 + wn*32 + j*16.
// LDS: 2 parity x 2 half x [128][64] bf16 per operand = 64 KB x2 = 128 KB.
// ---------------------------------------------------------------------------
__global__ __launch_bounds__(512, 2) void gemm_aug(
    const unsigned short* __restrict__ Xa, const unsigned short* __restrict__ Wa,
    const float* __restrict__ bias, float* __restrict__ out)
{
  __shared__ unsigned short lds_a[4 * HT];  // 64 KB
  __shared__ unsigned short lds_b[4 * HT];  // 64 KB

  const int tid = threadIdx.x;
  // T1: bijective XCD swizzle (512 wgs % 8 == 0). XCD x gets bm in
  // [x*8, x*8+8) x all 8 bn (bn fastest -> B panels reused across bm rows).
  const int lin = ((int)blockIdx.x & 7) * 64 + ((int)blockIdx.x >> 3);
  const int bm = lin >> 3, bn = lin & 7;
  const int w = tid >> 6, lane = tid & 63;
  const int wm = w >> 2, wn = w & 3;          // 2x4 wave grid
  const int quad = lane >> 4, m16 = lane & 15;

  f32x4 acc[8][4];
  #pragma unroll
  for (int i = 0; i < 8; ++i)
    #pragma unroll
    for (int j = 0; j < 4; ++j) acc[i][j] = f32x4{0.f, 0.f, 0.f, 0.f};

  const unsigned short* ga = Xa + (size_t)bm * 256 * KA;
  const unsigned short* gb = Wa + (size_t)bn * 256 * KA;

  // staging offsets: thread covers 16B chunks p=tid and p=512+tid of a
  // 128x8-chunk half-tile; chunk p1 is chunk p0 + 64 rows (same swizzle).
  Stg st;
  {
    int r = tid >> 3, c = (tid & 7) ^ (r & 7);
    st.so   = r * KA + c * 8;            // + koff (+64*KA for second load)
    st.dofs = (tid & ~63) * 8;           // wave-uniform LDS base (ushorts)
  }

  // fragment read bases; read chunk (kk*4+quad)^(m16&7) -> 2-way only (free)
  int cc[2];
  cc[0] = (quad ^ (m16 & 7)) * 8;
  cc[1] = ((4 + quad) ^ (m16 & 7)) * 8;
  const int rowA = (wm * 64 + m16) * 64;  // + i*1024 (+HT for ih=1)
  const int rowB = (wn * 32 + m16) * 64;  // + j*1024 (+HT for jh=1)

  // prologue: stage step 0's 4 half-tiles in first-use order; vmcnt(2)
  // retires A-h0,B-h0,B-h1 (R01's needs); A-h1(0) stays in flight
  // (= the steady-state invariant entering any step).
  stage_half(ga, lds_a, 0, st);                 // A-h0(0)
  stage_half(gb, lds_b, 0, st);                 // B-h0(0)
  stage_half(gb + 128 * KA, lds_b + HT, 0, st); // B-h1(0)
  stage_half(ga + 128 * KA, lds_a + HT, 0, st); // A-h1(0)
  asm volatile("s_waitcnt vmcnt(2)" ::: "memory");
  gate_barrier();

  for (int t = 0; t < NT - 1; ++t)
    kstep<6, 2, true>(t, ga, gb, lds_a, lds_b, st, rowA, rowB, cc, acc);
  kstep<0, -1, false>(NT - 1, ga, gb, lds_a, lds_b, st, rowA, rowB, cc, acc);

  // Epilogue: C/D layout col = lane&15, row = quad*4 + reg.
  // acc[ih*4+i][jh*2+j] -> row = bm*256 + ih*128 + wm*64 + i*16 + quad*4,
  //                        col = bn*256 + jh*128 + wn*32 + j*16 + m16.
  float bv[4];
  #pragma unroll
  for (int jj = 0; jj < 4; ++jj)
    bv[jj] = bias[bn * 256 + (jj >> 1) * 128 + wn * 32 + (jj & 1) * 16 + m16];
  #pragma unroll
  for (int I = 0; I < 8; ++I) {
    const int row0 = bm * 256 + (I >> 2) * 128 + wm * 64 + (I & 3) * 16 + quad * 4;
    #pragma unroll
    for (int jj = 0; jj < 4; ++jj) {
      const int col = bn * 256 + (jj >> 1) * 128 + wn * 32 + (jj & 1) * 16 + m16;
      #pragma unroll
      for (int r = 0; r < 4; ++r)
        out[(size_t)(row0 + r) * DOUT + col] = acc[I][jj][r] + bv[jj];
    }
  }
}

// ---------------------------------------------------------------------------
extern "C" void kernel_launch(void* const* d_in, const int* in_sizes, int n_in,
                              void* d_out, int out_size, void* d_ws, size_t ws_size,
                              hipStream_t stream) {
  const float* x    = (const float*)d_in[0];  // [4,4096,2048]
  const float* mask = (const float*)d_in[1];  // [4,4,4096,1]
  const float* W    = (const float*)d_in[2];  // [2048,2048]
  const float* bias = (const float*)d_in[3];  // [2048]
  const float* A    = (const float*)d_in[4];  // [4,16,2048] -> flat [64,2048]
  const float* Bw   = (const float*)d_in[5];  // [4,2048,16]
  float* out = (float*)d_out;

  // workspace layout:
  //   Xaug  [16384,2112] bf16 = 69,206,016 B
  //   Waug  [ 2048,2112] bf16 =  8,650,752 B
  //   Hpart [4,16384,64] f32  = 16,777,216 B
  // total = 94,633,984 bytes of d_ws
  unsigned short* Xaug = (unsigned short*)d_ws;
  unsigned short* Waug = Xaug + (size_t)M * KA;
  float* Hpart = (float*)(Waug + (size_t)DOUT * KA);

  pass1a_conv_hpart<<<dim3(M / 64 * KSPLIT), dim3(256), 0, stream>>>(x, A, Xaug, Hpart);
  pass1b_reduce_mask<<<dim3(M * 64 / 256), dim3(256), 0, stream>>>(Hpart, mask, Xaug);
  pass2_wcvt<<<dim3((DOUT * (DIN / 8)) / 256), dim3(256), 0, stream>>>(W, Bw, Waug);
  gemm_aug<<<dim3(512), dim3(512), 0, stream>>>(Xaug, Waug, bias, out);
}